// Round 4
// baseline (4190.599 us; speedup 1.0000x reference)
//
#include <hip/hip_runtime.h>
#include <hip/hip_bf16.h>
#include <math.h>

// Problem dims (fixed by reference)
#define NL   24
#define DDIM 768
#define ED   1536
#define NST  16
#define KC   4
#define DTR  48
#define VV   1024
#define LL   512
#define BB   2
#define MM   (BB*LL)      // 1024
#define SP   80           // DT_RANK + 2N

// scan chunking
#define NC   32           // chunks per sequence
#define CL   (LL/NC)      // 16 timesteps per chunk

// x_proj split-K
#define XKS  16           // K splits
#define XKC  (ED/XKS)     // 96 per split

// out_proj split-K
#define OPS  4            // splits
#define OPK  (ED/OPS)     // 384 K per split

typedef unsigned short u16;
typedef __bf16 bf16x8 __attribute__((ext_vector_type(8)));
typedef float  floatx4 __attribute__((ext_vector_type(4)));
typedef unsigned short ushort4v __attribute__((ext_vector_type(4)));

typedef const __attribute__((address_space(1))) void gvoid_t;
typedef __attribute__((address_space(3))) void svoid_t;

// async global->LDS, 16B per lane; LDS dest = wave-uniform base + lane*16
#define GLD16(g, l) __builtin_amdgcn_global_load_lds((gvoid_t*)(g), (svoid_t*)(l), 16, 0, 0)

__device__ __forceinline__ float softplusf(float x) {
    return fmaxf(x, 0.0f) + log1pf(expf(-fabsf(x)));
}
__device__ __forceinline__ float siluf(float x) {
    return x / (1.0f + expf(-x));
}
__device__ __forceinline__ u16 f2bf(float x) {
    unsigned int u = __builtin_bit_cast(unsigned int, x);
    u += 0x7FFFu + ((u >> 16) & 1u);   // round-to-nearest-even
    return (u16)(u >> 16);
}

// ---------------- fp32 -> bf16 bulk conversion (weights, once per call) ----
__global__ __launch_bounds__(256) void cvt_bf16_kernel(
        const float* __restrict__ in, u16* __restrict__ out, int n4)
{
    int stride = gridDim.x * 256;
    for (int i = blockIdx.x * 256 + threadIdx.x; i < n4; i += stride) {
        float4 v = reinterpret_cast<const float4*>(in)[i];
        ushort4v o = {f2bf(v.x), f2bf(v.y), f2bf(v.z), f2bf(v.w)};
        reinterpret_cast<ushort4v*>(out)[i] = o;
    }
}

// ---------------- embedding: h[m,:] = embed[src[l,b],:], m = b*L + l -------
__global__ __launch_bounds__(256) void embed_kernel(
        const int* __restrict__ src, const float* __restrict__ emb,
        float* __restrict__ h)
{
    int m = blockIdx.x;
    int b = m >> 9;           // m / L
    int l = m & (LL - 1);
    int v = src[l * BB + b];
    const float* er = emb + (size_t)v * DDIM;
    float* hr = h + (size_t)m * DDIM;
    for (int d = threadIdx.x; d < DDIM; d += 256) hr[d] = er[d];
}

// ------- rmsnorm (+ optional residual-reduce of out_proj partials) ---------
// nz>0: h[m,:] += sum_z part[z][m,:]  (written back to h), then normalize.
__global__ __launch_bounds__(256) void rmsnorm_res_kernel(
        float* __restrict__ h, const float* __restrict__ part, int nz,
        const float* __restrict__ w, u16* __restrict__ o)
{
    __shared__ float red[4];
    int m = blockIdx.x, tid = threadIdx.x;
    float* hr = h + (size_t)m * DDIM;
    float v0 = hr[tid], v1 = hr[tid + 256], v2 = hr[tid + 512];
    for (int z = 0; z < nz; z++) {
        const float* pr = part + ((size_t)z * MM + m) * DDIM;
        v0 += pr[tid]; v1 += pr[tid + 256]; v2 += pr[tid + 512];
    }
    if (nz > 0) {
        hr[tid] = v0; hr[tid + 256] = v1; hr[tid + 512] = v2;
    }
    float s = v0 * v0 + v1 * v1 + v2 * v2;
    #pragma unroll
    for (int off = 32; off; off >>= 1) s += __shfl_down(s, off);
    if ((tid & 63) == 0) red[tid >> 6] = s;
    __syncthreads();
    float tot = red[0] + red[1] + red[2] + red[3];
    float scale = rsqrtf(tot * (1.0f / DDIM) + 1e-5f);
    u16* orow = o + (size_t)m * DDIM;
    orow[tid]       = f2bf(v0 * scale * w[tid]);
    orow[tid + 256] = f2bf(v1 * scale * w[tid + 256]);
    orow[tid + 512] = f2bf(v2 * scale * w[tid + 512]);
}

// ============ bf16 MFMA GEMM, BM=128 x BN=32*BNF, BK=64, double-buffered ===
// A bf16 [M,lda], W bf16 [N,ldb] row-major (K-contiguous). 4 waves in 2x2;
// wave tile 64 x BNF*16 (4 x BNF 16x16 MFMAs per 32-k step, 2 per BK).
// LDS: [row][64k] bf16, 8-u16 chunks XOR-swizzled (slot = chunk ^ (row&7))
// via pre-swizzled global source + linear global_load_lds dest.
// 2-phase pipeline: stage(next buf) issued BEFORE compute(cur); single
// __syncthreads per K-step (drains vmcnt+lgkm -> next buf ready, cur safe).
// grid: x = N-tiles (XCD-friendly), y = M-tiles, z = K-splits (Kper each).
// MODE: 0 = fp32 store; 3 = logits store with [B,L]->[L,B] transpose;
//       4 = fp32 store to per-split partial C + z*MM*ldc
template<int BNF, int MODE>
__global__ __launch_bounds__(256) void gemm_bf16_d(
        const u16* __restrict__ A, int lda,
        const u16* __restrict__ W, int ldb,
        float* __restrict__ C, int ldc,
        int Kper)
{
    __shared__ __attribute__((aligned(16))) u16 As[2][128 * 64];
    __shared__ __attribute__((aligned(16))) u16 Bs[2][BNF * 32 * 64];
    int tid  = threadIdx.x;
    int lane = tid & 63;
    int wave = tid >> 6;
    int wm = wave >> 1, wn = wave & 1;
    int colBase = blockIdx.x * (BNF * 32);
    int rowBase = blockIdx.y * 128;
    int k0 = blockIdx.z * Kper;

    floatx4 acc[4][BNF];
    #pragma unroll
    for (int i = 0; i < 4; i++)
        #pragma unroll
        for (int j = 0; j < BNF; j++)
            acc[i][j] = (floatx4){0.f, 0.f, 0.f, 0.f};

    int kc = lane >> 4;      // k-chunk 0..3 within a 32-k MFMA step
    int lm = lane & 15;

    // staging: A has 1024 16B-chunks (4/thread), B has BNF*256 (BNF/thread).
    // chunk q -> row r=q>>3, LDS slot cs=q&7 holds global chunk cg=cs^(r&7).
    const u16* Ap[4];
    #pragma unroll
    for (int j = 0; j < 4; j++) {
        int q = (wave * 4 + j) * 64 + lane;
        int r = q >> 3, cg = (q & 7) ^ (r & 7);
        Ap[j] = A + (size_t)(rowBase + r) * lda + k0 + cg * 8;
    }
    const u16* Wp[BNF];
    #pragma unroll
    for (int j = 0; j < BNF; j++) {
        int q = (wave * BNF + j) * 64 + lane;
        int r = q >> 3, cg = (q & 7) ^ (r & 7);
        Wp[j] = W + (size_t)(colBase + r) * ldb + k0 + cg * 8;
    }

    auto stage = [&](int buf, int kk) {
        u16* as = &As[buf][0];
        u16* bs = &Bs[buf][0];
        #pragma unroll
        for (int j = 0; j < 4; j++) GLD16(Ap[j] + kk, as + (wave * 4 + j) * 512);
        #pragma unroll
        for (int j = 0; j < BNF; j++) GLD16(Wp[j] + kk, bs + (wave * BNF + j) * 512);
    };

    int nt = Kper >> 6;
    stage(0, 0);
    __syncthreads();
    for (int t = 0; t < nt; t++) {
        int cur = t & 1;
        if (t + 1 < nt) stage(cur ^ 1, (t + 1) * 64);
        #pragma unroll
        for (int ks = 0; ks < 2; ks++) {
            int ck = ks * 4 + kc;
            bf16x8 af[4], bw[BNF];
            #pragma unroll
            for (int i = 0; i < 4; i++) {
                int m = wm * 64 + i * 16 + lm;
                af[i] = *reinterpret_cast<const bf16x8*>(
                    &As[cur][m * 64 + ((ck ^ (m & 7)) * 8)]);
            }
            #pragma unroll
            for (int j = 0; j < BNF; j++) {
                int n = wn * (BNF * 16) + j * 16 + lm;
                bw[j] = *reinterpret_cast<const bf16x8*>(
                    &Bs[cur][n * 64 + ((ck ^ (n & 7)) * 8)]);
            }
            #pragma unroll
            for (int i = 0; i < 4; i++)
                #pragma unroll
                for (int j = 0; j < BNF; j++)
                    acc[i][j] = __builtin_amdgcn_mfma_f32_16x16x32_bf16(
                        af[i], bw[j], acc[i][j], 0, 0, 0);
        }
        __syncthreads();   // drains lgkm (cur reads done) + vmcnt (next ready)
    }

    // epilogue: D col = lane&15, row = (lane>>4)*4 + reg
    float* Cz = (MODE == 4) ? (C + (size_t)blockIdx.z * MM * ldc) : C;
    int c4 = (lane >> 4) * 4;
    #pragma unroll
    for (int i = 0; i < 4; i++) {
        #pragma unroll
        for (int j = 0; j < BNF; j++) {
            floatx4 v = acc[i][j];
            int col = colBase + wn * (BNF * 16) + j * 16 + lm;
            #pragma unroll
            for (int p = 0; p < 4; p++) {
                int row = rowBase + wm * 64 + i * 16 + c4 + p;
                if (MODE == 3) {
                    int l = row & (LL - 1), b = row >> 9;
                    Cz[((size_t)l * BB + b) * ldc + col] = v[p];
                } else {
                    Cz[(size_t)row * ldc + col] = v[p];
                }
            }
        }
    }
}

// -------- x_proj split-K with fused depthwise conv + SiLU ------------------
// grid (MM/64, XKS), block 256. A-tile elements uc[m][e] are computed on the
// fly from ug (causal K=4 conv + bias + SiLU), used for the GEMM AND written
// to ucb (each (m,e) computed exactly once across the grid).
__global__ __launch_bounds__(256) void xproj_conv_partial(
        const float* __restrict__ ug, const float* __restrict__ cw,
        const float* __restrict__ cb, const float* __restrict__ W,
        float* __restrict__ part, float* __restrict__ ucb)
{
    __shared__ float As[16][65];
    __shared__ float Ws[16][88];
    int tid = threadIdx.x;
    int tx = tid & 15;        // col base (5 cols spaced 16)
    int ty = tid >> 4;        // row base (4 rows spaced 16)
    int rowBase = blockIdx.x * 64;
    int k0 = blockIdx.y * XKC;
    float acc[4][5] = {};

    for (int kk = 0; kk < XKC; kk += 16) {
        #pragma unroll
        for (int i = 0; i < 4; i++) {
            int idx = tid + i * 256;
            int r = idx >> 4, kc = idx & 15;
            int m = rowBase + r;
            int e = k0 + kk + kc;
            int b = m >> 9, l = m & (LL - 1);
            float a = cb[e];
            #pragma unroll
            for (int k = 0; k < KC; k++) {
                int ll = l + k - (KC - 1);
                float uv = (ll >= 0) ? ug[((size_t)(b * LL + ll)) * (2 * ED) + e] : 0.0f;
                a = fmaf(uv, cw[e * KC + k], a);
            }
            a = siluf(a);
            As[kc][r] = a;
            ucb[(size_t)m * ED + e] = a;
        }
        #pragma unroll
        for (int i = 0; i < 5; i++) {
            int idx = tid + i * 256;        // 0..1279
            int c = idx >> 4, kc = idx & 15;
            Ws[kc][c] = W[(size_t)c * ED + k0 + kk + kc];
        }
        __syncthreads();
        #pragma unroll
        for (int k = 0; k < 16; k++) {
            float av[4], bv[5];
            #pragma unroll
            for (int i = 0; i < 4; i++) av[i] = As[k][ty + 16 * i];
            #pragma unroll
            for (int j = 0; j < 5; j++) bv[j] = Ws[k][tx + 16 * j];
            #pragma unroll
            for (int i = 0; i < 4; i++)
                #pragma unroll
                for (int j = 0; j < 5; j++)
                    acc[i][j] = fmaf(av[i], bv[j], acc[i][j]);
        }
        __syncthreads();
    }

    float* p = part + ((size_t)blockIdx.y * MM + rowBase) * SP;
    #pragma unroll
    for (int i = 0; i < 4; i++)
        #pragma unroll
        for (int j = 0; j < 5; j++)
            p[(ty + 16 * i) * SP + tx + 16 * j] = acc[i][j];
}

// reduce 16 partial slices -> spb[m][0:80]  (float4 vectorized)
__global__ __launch_bounds__(256) void xproj_reduce(
        const float* __restrict__ part, float* __restrict__ spb)
{
    int idx = blockIdx.x * 256 + threadIdx.x;   // over MM*SP/4 = 20480
    float4 s = {0.f, 0.f, 0.f, 0.f};
    #pragma unroll
    for (int ks = 0; ks < XKS; ks++) {
        float4 v = reinterpret_cast<const float4*>(part + (size_t)ks * MM * SP)[idx];
        s.x += v.x; s.y += v.y; s.z += v.z; s.w += v.w;
    }
    reinterpret_cast<float4*>(spb)[idx] = s;
}

// ================= chunked selective scan (dt fused) =======================
// Per block: 256 e's, one chunk c, one batch b. spb rows for the chunk are
// staged in LDS (serves dt dot-product and B/C reads). dt[m][e] =
// softplus(dot48(spb[m,:48], dt_w[e,:]) + dt_b[e]) recomputed per pass.
__global__ __launch_bounds__(256) void scan_pass1(
        const float* __restrict__ spb, const float* __restrict__ dt_w,
        const float* __restrict__ dt_b, const float* __restrict__ ucb,
        const float* __restrict__ A_log,
        float* __restrict__ hfin, float* __restrict__ sumdt)
{
    __shared__ float sp_s[CL][SP];    // 16 x 80 floats = 5 KB
    int tid = threadIdx.x;
    int e = blockIdx.x * 256 + tid;
    int c = blockIdx.y;
    int b = blockIdx.z;
    int m0 = b * LL + c * CL;
    // stage spb rows (chunk) into LDS, float4
    for (int i = tid; i < CL * SP / 4; i += 256) {
        reinterpret_cast<float4*>(&sp_s[0][0])[i] =
            reinterpret_cast<const float4*>(spb + (size_t)m0 * SP)[i];
    }
    // dt_w row in registers (48 floats)
    float wdt[DTR];
    const float4* wp = reinterpret_cast<const float4*>(dt_w + (size_t)e * DTR);
    #pragma unroll
    for (int q = 0; q < DTR / 4; q++) {
        float4 v = wp[q];
        wdt[4*q+0] = v.x; wdt[4*q+1] = v.y; wdt[4*q+2] = v.z; wdt[4*q+3] = v.w;
    }
    float bias = dt_b[e];
    float a[NST], h[NST];
    const float4* ap = reinterpret_cast<const float4*>(A_log + (size_t)e * NST);
    #pragma unroll
    for (int q = 0; q < 4; q++) {
        float4 v = ap[q];
        a[4*q+0] = -expf(v.x); a[4*q+1] = -expf(v.y);
        a[4*q+2] = -expf(v.z); a[4*q+3] = -expf(v.w);
    }
    #pragma unroll
    for (int n = 0; n < NST; n++) h[n] = 0.0f;
    __syncthreads();

    float sdt = 0.0f;
    for (int l = 0; l < CL; l++) {
        // dt = softplus(dot48 + bias), sequential k order
        float dacc = 0.0f;
        #pragma unroll
        for (int q = 0; q < DTR / 4; q++) {
            float4 s4 = *reinterpret_cast<const float4*>(&sp_s[l][4 * q]);
            dacc = fmaf(s4.x, wdt[4*q+0], dacc);
            dacc = fmaf(s4.y, wdt[4*q+1], dacc);
            dacc = fmaf(s4.z, wdt[4*q+2], dacc);
            dacc = fmaf(s4.w, wdt[4*q+3], dacc);
        }
        float dtv = softplusf(dacc + bias);
        float ucv = ucb[(size_t)(m0 + l) * ED + e];
        float x = dtv * ucv;
        sdt += dtv;
        #pragma unroll
        for (int q = 0; q < 4; q++) {
            float4 bv = *reinterpret_cast<const float4*>(&sp_s[l][DTR + 4 * q]);
            h[4*q+0] = fmaf(expf(dtv * a[4*q+0]), h[4*q+0], x * bv.x);
            h[4*q+1] = fmaf(expf(dtv * a[4*q+1]), h[4*q+1], x * bv.y);
            h[4*q+2] = fmaf(expf(dtv * a[4*q+2]), h[4*q+2], x * bv.z);
            h[4*q+3] = fmaf(expf(dtv * a[4*q+3]), h[4*q+3], x * bv.w);
        }
    }
    float* hf = hfin + (((size_t)(b * ED + e)) * NC + c) * NST;
    #pragma unroll
    for (int n = 0; n < NST; n++) hf[n] = h[n];
    sumdt[((size_t)(b * ED + e)) * NC + c] = sdt;
}

// pass2: dt fused as above; chunk-prefix (old scan_mid) computed in-block
// from hfin/sumdt; y written as bf16.
__global__ __launch_bounds__(256) void scan_pass2(
        const float* __restrict__ spb, const float* __restrict__ dt_w,
        const float* __restrict__ dt_b, const float* __restrict__ ucb,
        const float* __restrict__ ugb, const float* __restrict__ A_log,
        const float* __restrict__ Dp, const float* __restrict__ hfin,
        const float* __restrict__ sumdt, u16* __restrict__ yb)
{
    __shared__ float sp_s[CL][SP];
    int tid = threadIdx.x;
    int e = blockIdx.x * 256 + tid;
    int c = blockIdx.y;
    int b = blockIdx.z;
    int m0 = b * LL + c * CL;
    for (int i = tid; i < CL * SP / 4; i += 256) {
        reinterpret_cast<float4*>(&sp_s[0][0])[i] =
            reinterpret_cast<const float4*>(spb + (size_t)m0 * SP)[i];
    }
    float wdt[DTR];
    const float4* wp = reinterpret_cast<const float4*>(dt_w + (size_t)e * DTR);
    #pragma unroll
    for (int q = 0; q < DTR / 4; q++) {
        float4 v = wp[q];
        wdt[4*q+0] = v.x; wdt[4*q+1] = v.y; wdt[4*q+2] = v.z; wdt[4*q+3] = v.w;
    }
    float bias = dt_b[e];
    float a[NST], h[NST];
    const float4* ap = reinterpret_cast<const float4*>(A_log + (size_t)e * NST);
    #pragma unroll
    for (int q = 0; q < 4; q++) {
        float4 v = ap[q];
        a[4*q+0] = -expf(v.x); a[4*q+1] = -expf(v.y);
        a[4*q+2] = -expf(v.z); a[4*q+3] = -expf(v.w);
    }
    // chunk-prefix: h(c) = scan over chunks 0..c-1 (same recurrence as the
    // old scan_mid, fp32 fma order identical)
    #pragma unroll
    for (int n = 0; n < NST; n++) h[n] = 0.0f;
    {
        size_t be = (size_t)(b * ED + e);
        const float* sd = sumdt + be * NC;
        const float* hfp = hfin + be * NC * NST;
        for (int cp = 0; cp < c; cp++) {
            float f = sd[cp];
            const float4* hq = reinterpret_cast<const float4*>(hfp + cp * NST);
            #pragma unroll
            for (int q = 0; q < 4; q++) {
                float4 hv = hq[q];
                h[4*q+0] = fmaf(expf(a[4*q+0] * f), h[4*q+0], hv.x);
                h[4*q+1] = fmaf(expf(a[4*q+1] * f), h[4*q+1], hv.y);
                h[4*q+2] = fmaf(expf(a[4*q+2] * f), h[4*q+2], hv.z);
                h[4*q+3] = fmaf(expf(a[4*q+3] * f), h[4*q+3], hv.w);
            }
        }
    }
    float dpv = Dp[e];
    __syncthreads();

    for (int l = 0; l < CL; l++) {
        int m = m0 + l;
        float dacc = 0.0f;
        #pragma unroll
        for (int q = 0; q < DTR / 4; q++) {
            float4 s4 = *reinterpret_cast<const float4*>(&sp_s[l][4 * q]);
            dacc = fmaf(s4.x, wdt[4*q+0], dacc);
            dacc = fmaf(s4.y, wdt[4*q+1], dacc);
            dacc = fmaf(s4.z, wdt[4*q+2], dacc);
            dacc = fmaf(s4.w, wdt[4*q+3], dacc);
        }
        float dtv = softplusf(dacc + bias);
        float ucv = ucb[(size_t)m * ED + e];
        float g = ugb[(size_t)m * (2 * ED) + ED + e];
        float x = dtv * ucv;
        float y0 = 0.0f, y1 = 0.0f, y2 = 0.0f, y3 = 0.0f;
        #pragma unroll
        for (int q = 0; q < 4; q++) {
            float4 bv = *reinterpret_cast<const float4*>(&sp_s[l][DTR + 4 * q]);
            float4 cv = *reinterpret_cast<const float4*>(&sp_s[l][DTR + NST + 4 * q]);
            h[4*q+0] = fmaf(expf(dtv * a[4*q+0]), h[4*q+0], x * bv.x);
            h[4*q+1] = fmaf(expf(dtv * a[4*q+1]), h[4*q+1], x * bv.y);
            h[4*q+2] = fmaf(expf(dtv * a[4*q+2]), h[4*q+2], x * bv.z);
            h[4*q+3] = fmaf(expf(dtv * a[4*q+3]), h[4*q+3], x * bv.w);
            y0 = fmaf(h[4*q+0], cv.x, y0);
            y1 = fmaf(h[4*q+1], cv.y, y1);
            y2 = fmaf(h[4*q+2], cv.z, y2);
            y3 = fmaf(h[4*q+3], cv.w, y3);
        }
        float yv = (y0 + y1) + (y2 + y3) + ucv * dpv;
        yb[(size_t)m * ED + e] = f2bf(yv * siluf(g));
    }
}

extern "C" void kernel_launch(void* const* d_in, const int* in_sizes, int n_in,
                              void* d_out, int out_size, void* d_ws, size_t ws_size,
                              hipStream_t stream) {
    const int*   src    = (const int*)  d_in[0];
    const float* emb    = (const float*)d_in[1];
    const float* norm_w = (const float*)d_in[2];
    const float* in_prj = (const float*)d_in[3];
    const float* conv_w = (const float*)d_in[4];
    const float* conv_b = (const float*)d_in[5];
    const float* x_prj  = (const float*)d_in[6];
    const float* dt_w   = (const float*)d_in[7];
    const float* dt_b   = (const float*)d_in[8];
    const float* A_log  = (const float*)d_in[9];
    const float* Dp     = (const float*)d_in[10];
    const float* out_p  = (const float*)d_in[11];
    const float* normf  = (const float*)d_in[12];
    float* out = (float*)d_out;

    float* ws    = (float*)d_ws;
    float* h     = ws;                              // M*D
    float* xn_f  = h     + (size_t)MM * DDIM;       // M*D slot (bf16 used)
    float* ug    = xn_f  + (size_t)MM * DDIM;       // M*2ED
    float* ucb   = ug    + (size_t)MM * 2 * ED;     // M*ED
    float* spb   = ucb   + (size_t)MM * ED;         // M*SP
    float* yb_f  = spb   + (size_t)MM * SP;         // M*ED slot (bf16 used)
    float* hfin  = yb_f  + (size_t)MM * ED;         // B*ED*NC*NST (also x_proj partials)
    float* sumdt = hfin  + (size_t)BB * ED * NC * NST; // B*ED*NC
    float* wend  = sumdt + (size_t)BB * ED * NC;
    float* xpart = hfin;                            // reuse: dead before scan_pass1

    u16* xn = (u16*)xn_f;
    u16* yb = (u16*)yb_f;
    u16* wbf_in  = (u16*)wend;                         // NL*2ED*D bf16
    u16* wbf_out = wbf_in  + (size_t)NL * 2 * ED * DDIM;  // NL*D*ED bf16
    u16* wbf_emb = wbf_out + (size_t)NL * DDIM * ED;      // V*D bf16
    float* opart = (float*)(wbf_emb + (size_t)VV * DDIM); // OPS * M*D fp32

    // one-time weight conversion (bit-identical RNE rounding to old staging)
    cvt_bf16_kernel<<<2048, 256, 0, stream>>>(in_prj, wbf_in, NL * 2 * ED * DDIM / 4);
    cvt_bf16_kernel<<<2048, 256, 0, stream>>>(out_p, wbf_out, NL * DDIM * ED / 4);
    cvt_bf16_kernel<<<256, 256, 0, stream>>>(emb, wbf_emb, VV * DDIM / 4);

    embed_kernel<<<MM, 256, 0, stream>>>(src, emb, h);

    for (int layer = 0; layer < NL; layer++) {
        // rmsnorm; for layer>0 also folds in the 4 out_proj partials (h update)
        rmsnorm_res_kernel<<<MM, 256, 0, stream>>>(
            h, opart, layer == 0 ? 0 : OPS, norm_w + (size_t)layer * DDIM, xn);
        // ug = xn @ in_proj^T   [M, 2ED]  (grid 48x8 = 384 blocks, dbuf)
        gemm_bf16_d<2, 0><<<dim3(2 * ED / 64, MM / 128, 1), 256, 0, stream>>>(
            xn, DDIM, wbf_in + (size_t)layer * 2 * ED * DDIM, DDIM,
            ug, 2 * ED, DDIM);
        // sp partials = silu(conv(u)) @ x_proj^T; also writes ucb
        xproj_conv_partial<<<dim3(MM / 64, XKS), 256, 0, stream>>>(
            ug, conv_w + (size_t)layer * ED * KC, conv_b + (size_t)layer * ED,
            x_prj + (size_t)layer * SP * ED, xpart, ucb);
        xproj_reduce<<<MM * SP / 1024, 256, 0, stream>>>(xpart, spb);
        // chunked scan, dt fused (reads spb via LDS, dt_w row per thread)
        scan_pass1<<<dim3(ED / 256, NC, BB), 256, 0, stream>>>(
            spb, dt_w + (size_t)layer * ED * DTR, dt_b + (size_t)layer * ED,
            ucb, A_log + (size_t)layer * ED * NST, hfin, sumdt);
        scan_pass2<<<dim3(ED / 256, NC, BB), 256, 0, stream>>>(
            spb, dt_w + (size_t)layer * ED * DTR, dt_b + (size_t)layer * ED,
            ucb, ug, A_log + (size_t)layer * ED * NST,
            Dp + (size_t)layer * ED, hfin, sumdt, yb);
        // out_proj partials: opart[z] = y @ out_proj^T[k-slice z]
        // (grid 12x8x4 = 384 blocks; reduction folds into next rmsnorm)
        gemm_bf16_d<2, 4><<<dim3(DDIM / 64, MM / 128, OPS), 256, 0, stream>>>(
            yb, ED, wbf_out + (size_t)layer * DDIM * ED, ED,
            opart, DDIM, OPK);
    }

    // final rmsnorm folds in last layer's out_proj partials
    rmsnorm_res_kernel<<<MM, 256, 0, stream>>>(h, opart, OPS, normf, xn);
    // logits = xn @ embed^T, stored transposed to [L, B, V]  (BN=32: 256 blk)
    gemm_bf16_d<1, 3><<<dim3(VV / 32, MM / 128, 1), 256, 0, stream>>>(
        xn, DDIM, wbf_emb, DDIM, out, VV, DDIM);
}

// Round 6
// 3374.209 us; speedup vs baseline: 1.2420x; 1.2420x over previous
//
#include <hip/hip_runtime.h>
#include <hip/hip_bf16.h>
#include <math.h>

// Problem dims (fixed by reference)
#define NL   24
#define DDIM 768
#define ED   1536
#define NST  16
#define KC   4
#define DTR  48
#define VV   1024
#define LL   512
#define BB   2
#define MM   (BB*LL)      // 1024
#define SP   80           // DT_RANK + 2N

// scan chunking
#define NC   32           // chunks per sequence
#define CL   (LL/NC)      // 16 timesteps per chunk

// x_proj split-K
#define XKS  32           // K splits (512 blocks = 2.0/CU uniform)
#define XKC  (ED/XKS)     // 48 per split

// out_proj split-K
#define OPS  4            // splits
#define OPK  (ED/OPS)     // 384 K per split

typedef unsigned short u16;
typedef __bf16 bf16x8 __attribute__((ext_vector_type(8)));
typedef float  floatx4 __attribute__((ext_vector_type(4)));
typedef unsigned short ushort4v __attribute__((ext_vector_type(4)));

typedef const __attribute__((address_space(1))) void gvoid_t;
typedef __attribute__((address_space(3))) void svoid_t;

// async global->LDS, 16B per lane; LDS dest = wave-uniform base + lane*16
#define GLD16(g, l) __builtin_amdgcn_global_load_lds((gvoid_t*)(g), (svoid_t*)(l), 16, 0, 0)

__device__ __forceinline__ float softplusf(float x) {
    return fmaxf(x, 0.0f) + log1pf(expf(-fabsf(x)));
}
__device__ __forceinline__ float siluf(float x) {
    return x / (1.0f + expf(-x));
}
__device__ __forceinline__ u16 f2bf(float x) {
    unsigned int u = __builtin_bit_cast(unsigned int, x);
    u += 0x7FFFu + ((u >> 16) & 1u);   // round-to-nearest-even
    return (u16)(u >> 16);
}

// ---------------- fp32 -> bf16 bulk conversion (weights, once per call) ----
__global__ __launch_bounds__(256) void cvt_bf16_kernel(
        const float* __restrict__ in, u16* __restrict__ out, int n4)
{
    int stride = gridDim.x * 256;
    for (int i = blockIdx.x * 256 + threadIdx.x; i < n4; i += stride) {
        float4 v = reinterpret_cast<const float4*>(in)[i];
        ushort4v o = {f2bf(v.x), f2bf(v.y), f2bf(v.z), f2bf(v.w)};
        reinterpret_cast<ushort4v*>(out)[i] = o;
    }
}

// ---------------- embedding: h[m,:] = embed[src[l,b],:], m = b*L + l -------
__global__ __launch_bounds__(256) void embed_kernel(
        const int* __restrict__ src, const float* __restrict__ emb,
        float* __restrict__ h)
{
    int m = blockIdx.x;
    int b = m >> 9;           // m / L
    int l = m & (LL - 1);
    int v = src[l * BB + b];
    const float* er = emb + (size_t)v * DDIM;
    float* hr = h + (size_t)m * DDIM;
    for (int d = threadIdx.x; d < DDIM; d += 256) hr[d] = er[d];
}

// ------- rmsnorm (+ optional residual-reduce of out_proj partials) ---------
// nz>0: h[m,:] += sum_z part[z][m,:]  (written back to h), then normalize.
__global__ __launch_bounds__(256) void rmsnorm_res_kernel(
        float* __restrict__ h, const float* __restrict__ part, int nz,
        const float* __restrict__ w, u16* __restrict__ o)
{
    __shared__ float red[4];
    int m = blockIdx.x, tid = threadIdx.x;
    float* hr = h + (size_t)m * DDIM;
    float v0 = hr[tid], v1 = hr[tid + 256], v2 = hr[tid + 512];
    for (int z = 0; z < nz; z++) {
        const float* pr = part + ((size_t)z * MM + m) * DDIM;
        v0 += pr[tid]; v1 += pr[tid + 256]; v2 += pr[tid + 512];
    }
    if (nz > 0) {
        hr[tid] = v0; hr[tid + 256] = v1; hr[tid + 512] = v2;
    }
    float s = v0 * v0 + v1 * v1 + v2 * v2;
    #pragma unroll
    for (int off = 32; off; off >>= 1) s += __shfl_down(s, off);
    if ((tid & 63) == 0) red[tid >> 6] = s;
    __syncthreads();
    float tot = red[0] + red[1] + red[2] + red[3];
    float scale = rsqrtf(tot * (1.0f / DDIM) + 1e-5f);
    u16* orow = o + (size_t)m * DDIM;
    orow[tid]       = f2bf(v0 * scale * w[tid]);
    orow[tid + 256] = f2bf(v1 * scale * w[tid + 256]);
    orow[tid + 512] = f2bf(v2 * scale * w[tid + 512]);
}

// ============ bf16 MFMA GEMM, BM=128 x BN=32*BNF, BK=64, double-buffered ===
// A bf16 [M,lda], W bf16 [N,ldb] row-major (K-contiguous). 4 waves in 2x2;
// wave tile 64 x BNF*16 (4 x BNF 16x16 MFMAs per 32-k step, 2 per BK).
// LDS: [row][64k] bf16, 8-u16 chunks XOR-swizzled (slot = chunk ^ (row&7))
// via pre-swizzled global source + linear global_load_lds dest.
// 2-phase pipeline: stage(next buf) issued BEFORE compute(cur); single
// __syncthreads per K-step (drains vmcnt+lgkm -> next buf ready, cur safe).
// grid: x = N-tiles (XCD-friendly), y = M-tiles, z = K-splits (Kper each).
// MODE: 0 = fp32 store; 3 = logits store with [B,L]->[L,B] transpose;
//       4 = fp32 store to per-split partial C + z*MM*ldc
template<int BNF, int MODE>
__global__ __launch_bounds__(256) void gemm_bf16_d(
        const u16* __restrict__ A, int lda,
        const u16* __restrict__ W, int ldb,
        float* __restrict__ C, int ldc,
        int Kper)
{
    __shared__ __attribute__((aligned(16))) u16 As[2][128 * 64];
    __shared__ __attribute__((aligned(16))) u16 Bs[2][BNF * 32 * 64];
    int tid  = threadIdx.x;
    int lane = tid & 63;
    int wave = tid >> 6;
    int wm = wave >> 1, wn = wave & 1;
    int colBase = blockIdx.x * (BNF * 32);
    int rowBase = blockIdx.y * 128;
    int k0 = blockIdx.z * Kper;

    floatx4 acc[4][BNF];
    #pragma unroll
    for (int i = 0; i < 4; i++)
        #pragma unroll
        for (int j = 0; j < BNF; j++)
            acc[i][j] = (floatx4){0.f, 0.f, 0.f, 0.f};

    int kc = lane >> 4;      // k-chunk 0..3 within a 32-k MFMA step
    int lm = lane & 15;

    // staging: A has 1024 16B-chunks (4/thread), B has BNF*256 (BNF/thread).
    // chunk q -> row r=q>>3, LDS slot cs=q&7 holds global chunk cg=cs^(r&7).
    const u16* Ap[4];
    #pragma unroll
    for (int j = 0; j < 4; j++) {
        int q = (wave * 4 + j) * 64 + lane;
        int r = q >> 3, cg = (q & 7) ^ (r & 7);
        Ap[j] = A + (size_t)(rowBase + r) * lda + k0 + cg * 8;
    }
    const u16* Wp[BNF];
    #pragma unroll
    for (int j = 0; j < BNF; j++) {
        int q = (wave * BNF + j) * 64 + lane;
        int r = q >> 3, cg = (q & 7) ^ (r & 7);
        Wp[j] = W + (size_t)(colBase + r) * ldb + k0 + cg * 8;
    }

    auto stage = [&](int buf, int kk) {
        u16* as = &As[buf][0];
        u16* bs = &Bs[buf][0];
        #pragma unroll
        for (int j = 0; j < 4; j++) GLD16(Ap[j] + kk, as + (wave * 4 + j) * 512);
        #pragma unroll
        for (int j = 0; j < BNF; j++) GLD16(Wp[j] + kk, bs + (wave * BNF + j) * 512);
    };

    int nt = Kper >> 6;
    stage(0, 0);
    __syncthreads();
    for (int t = 0; t < nt; t++) {
        int cur = t & 1;
        if (t + 1 < nt) stage(cur ^ 1, (t + 1) * 64);
        #pragma unroll
        for (int ks = 0; ks < 2; ks++) {
            int ck = ks * 4 + kc;
            bf16x8 af[4], bw[BNF];
            #pragma unroll
            for (int i = 0; i < 4; i++) {
                int m = wm * 64 + i * 16 + lm;
                af[i] = *reinterpret_cast<const bf16x8*>(
                    &As[cur][m * 64 + ((ck ^ (m & 7)) * 8)]);
            }
            #pragma unroll
            for (int j = 0; j < BNF; j++) {
                int n = wn * (BNF * 16) + j * 16 + lm;
                bw[j] = *reinterpret_cast<const bf16x8*>(
                    &Bs[cur][n * 64 + ((ck ^ (n & 7)) * 8)]);
            }
            #pragma unroll
            for (int i = 0; i < 4; i++)
                #pragma unroll
                for (int j = 0; j < BNF; j++)
                    acc[i][j] = __builtin_amdgcn_mfma_f32_16x16x32_bf16(
                        af[i], bw[j], acc[i][j], 0, 0, 0);
        }
        __syncthreads();   // drains lgkm (cur reads done) + vmcnt (next ready)
    }

    // epilogue: D col = lane&15, row = (lane>>4)*4 + reg
    float* Cz = (MODE == 4) ? (C + (size_t)blockIdx.z * MM * ldc) : C;
    int c4 = (lane >> 4) * 4;
    #pragma unroll
    for (int i = 0; i < 4; i++) {
        #pragma unroll
        for (int j = 0; j < BNF; j++) {
            floatx4 v = acc[i][j];
            int col = colBase + wn * (BNF * 16) + j * 16 + lm;
            #pragma unroll
            for (int p = 0; p < 4; p++) {
                int row = rowBase + wm * 64 + i * 16 + c4 + p;
                if (MODE == 3) {
                    int l = row & (LL - 1), b = row >> 9;
                    Cz[((size_t)l * BB + b) * ldc + col] = v[p];
                } else {
                    Cz[(size_t)row * ldc + col] = v[p];
                }
            }
        }
    }
}

// ---------------- generic fp32 SGEMM (dt GEMM) -----------------------------
// modes: 0 = store; 1 = softplus(acc + bias[n])
__global__ __launch_bounds__(256) void sgemm_nt(
        const float* __restrict__ A, int lda,
        const float* __restrict__ W, int ldb,
        float* __restrict__ C, int ldc,
        int Nmat, int Kdim, int mode, const float* __restrict__ bias)
{
    __shared__ float As[16][65];
    __shared__ float Ws[16][65];
    int tid = threadIdx.x;
    int tx = tid & 15, ty = tid >> 4;
    int rowBase = blockIdx.x * 64;
    int colBase = blockIdx.y * 64;
    float acc[4][4] = {};

    for (int kk = 0; kk < Kdim; kk += 16) {
        #pragma unroll
        for (int i = 0; i < 4; i++) {
            int idx = tid + i * 256;
            int r = idx >> 4, kc = idx & 15;
            As[kc][r] = A[(size_t)(rowBase + r) * lda + kk + kc];
            int cG = colBase + r;
            Ws[kc][r] = (cG < Nmat) ? W[(size_t)cG * ldb + kk + kc] : 0.0f;
        }
        __syncthreads();
        #pragma unroll
        for (int k = 0; k < 16; k++) {
            float av[4], bv[4];
            #pragma unroll
            for (int i = 0; i < 4; i++) av[i] = As[k][ty + 16 * i];
            #pragma unroll
            for (int j = 0; j < 4; j++) bv[j] = Ws[k][tx + 16 * j];
            #pragma unroll
            for (int i = 0; i < 4; i++)
                #pragma unroll
                for (int j = 0; j < 4; j++)
                    acc[i][j] = fmaf(av[i], bv[j], acc[i][j]);
        }
        __syncthreads();
    }

    #pragma unroll
    for (int i = 0; i < 4; i++) {
        int m = rowBase + ty + 16 * i;
        #pragma unroll
        for (int j = 0; j < 4; j++) {
            int n = colBase + tx + 16 * j;
            if (n >= Nmat) continue;
            float v = acc[i][j];
            if (mode == 0) {
                C[(size_t)m * ldc + n] = v;
            } else {
                C[(size_t)m * ldc + n] = softplusf(v + bias[n]);
            }
        }
    }
}

// -------- x_proj split-K with fused depthwise conv + SiLU ------------------
// grid (MM/64, XKS), block 256. A-tile elements uc[m][e] are computed on the
// fly from ug (causal K=4 conv + bias + SiLU), used for the GEMM AND written
// to ucb (each (m,e) computed exactly once across the grid).
__global__ __launch_bounds__(256) void xproj_conv_partial(
        const float* __restrict__ ug, const float* __restrict__ cw,
        const float* __restrict__ cb, const float* __restrict__ W,
        float* __restrict__ part, float* __restrict__ ucb)
{
    __shared__ float As[16][65];
    __shared__ float Ws[16][88];
    int tid = threadIdx.x;
    int tx = tid & 15;        // col base (5 cols spaced 16)
    int ty = tid >> 4;        // row base (4 rows spaced 16)
    int rowBase = blockIdx.x * 64;
    int k0 = blockIdx.y * XKC;
    float acc[4][5] = {};

    for (int kk = 0; kk < XKC; kk += 16) {
        #pragma unroll
        for (int i = 0; i < 4; i++) {
            int idx = tid + i * 256;
            int r = idx >> 4, kc = idx & 15;
            int m = rowBase + r;
            int e = k0 + kk + kc;
            int b = m >> 9, l = m & (LL - 1);
            float a = cb[e];
            #pragma unroll
            for (int k = 0; k < KC; k++) {
                int ll = l + k - (KC - 1);
                float uv = (ll >= 0) ? ug[((size_t)(b * LL + ll)) * (2 * ED) + e] : 0.0f;
                a = fmaf(uv, cw[e * KC + k], a);
            }
            a = siluf(a);
            As[kc][r] = a;
            ucb[(size_t)m * ED + e] = a;
        }
        #pragma unroll
        for (int i = 0; i < 5; i++) {
            int idx = tid + i * 256;        // 0..1279
            int c = idx >> 4, kc = idx & 15;
            Ws[kc][c] = W[(size_t)c * ED + k0 + kk + kc];
        }
        __syncthreads();
        #pragma unroll
        for (int k = 0; k < 16; k++) {
            float av[4], bv[5];
            #pragma unroll
            for (int i = 0; i < 4; i++) av[i] = As[k][ty + 16 * i];
            #pragma unroll
            for (int j = 0; j < 5; j++) bv[j] = Ws[k][tx + 16 * j];
            #pragma unroll
            for (int i = 0; i < 4; i++)
                #pragma unroll
                for (int j = 0; j < 5; j++)
                    acc[i][j] = fmaf(av[i], bv[j], acc[i][j]);
        }
        __syncthreads();
    }

    float* p = part + ((size_t)blockIdx.y * MM + rowBase) * SP;
    #pragma unroll
    for (int i = 0; i < 4; i++)
        #pragma unroll
        for (int j = 0; j < 5; j++)
            p[(ty + 16 * i) * SP + tx + 16 * j] = acc[i][j];
}

// reduce XKS partial slices -> spb[m][0:80]  (float4 vectorized)
__global__ __launch_bounds__(256) void xproj_reduce(
        const float* __restrict__ part, float* __restrict__ spb)
{
    int idx = blockIdx.x * 256 + threadIdx.x;   // over MM*SP/4 = 20480
    float4 s = {0.f, 0.f, 0.f, 0.f};
    #pragma unroll
    for (int ks = 0; ks < XKS; ks++) {
        float4 v = reinterpret_cast<const float4*>(part + (size_t)ks * MM * SP)[idx];
        s.x += v.x; s.y += v.y; s.z += v.z; s.w += v.w;
    }
    reinterpret_cast<float4*>(spb)[idx] = s;
}

// ================= chunked selective scan ==================================
__global__ __launch_bounds__(256) void scan_pass1(
        const float* __restrict__ dtb, const float* __restrict__ ucb,
        const float* __restrict__ spb, const float* __restrict__ A_log,
        float* __restrict__ hfin, float* __restrict__ sumdt)
{
    int e = blockIdx.x * 256 + threadIdx.x;
    int c = blockIdx.y;
    int b = blockIdx.z;
    float a[NST], h[NST];
    const float4* ap = reinterpret_cast<const float4*>(A_log + (size_t)e * NST);
    #pragma unroll
    for (int q = 0; q < 4; q++) {
        float4 v = ap[q];
        a[4*q+0] = -expf(v.x); a[4*q+1] = -expf(v.y);
        a[4*q+2] = -expf(v.z); a[4*q+3] = -expf(v.w);
    }
    #pragma unroll
    for (int n = 0; n < NST; n++) h[n] = 0.0f;
    float sdt = 0.0f;
    int m0 = b * LL + c * CL;
    for (int l = 0; l < CL; l++) {
        int m = m0 + l;
        float dtv = dtb[(size_t)m * ED + e];
        float ucv = ucb[(size_t)m * ED + e];
        const float4* bp = reinterpret_cast<const float4*>(spb + (size_t)m * SP + DTR);
        float x = dtv * ucv;
        sdt += dtv;
        #pragma unroll
        for (int q = 0; q < 4; q++) {
            float4 bv = bp[q];
            h[4*q+0] = fmaf(expf(dtv * a[4*q+0]), h[4*q+0], x * bv.x);
            h[4*q+1] = fmaf(expf(dtv * a[4*q+1]), h[4*q+1], x * bv.y);
            h[4*q+2] = fmaf(expf(dtv * a[4*q+2]), h[4*q+2], x * bv.z);
            h[4*q+3] = fmaf(expf(dtv * a[4*q+3]), h[4*q+3], x * bv.w);
        }
    }
    float* hf = hfin + (((size_t)(b * ED + e)) * NC + c) * NST;
    #pragma unroll
    for (int n = 0; n < NST; n++) hf[n] = h[n];
    sumdt[((size_t)(b * ED + e)) * NC + c] = sdt;
}

__global__ __launch_bounds__(256) void scan_mid(
        const float* __restrict__ hfin, const float* __restrict__ sumdt,
        const float* __restrict__ A_log, float* __restrict__ hstart)
{
    int gid = blockIdx.x * 256 + threadIdx.x;   // (b*ED+e)*16 + n
    int n = gid & 15;
    int be = gid >> 4;
    int e = be % ED;
    float a = -expf(A_log[(size_t)e * NST + n]);
    float h = 0.0f;
    const float* hf = hfin + (size_t)be * NC * NST;
    const float* sd = sumdt + (size_t)be * NC;
    float* hs = hstart + (size_t)be * NC * NST;
    for (int c = 0; c < NC; c++) {
        hs[c * NST + n] = h;
        h = fmaf(expf(a * sd[c]), h, hf[c * NST + n]);
    }
}

__global__ __launch_bounds__(256) void scan_pass2(
        const float* __restrict__ dtb, const float* __restrict__ ucb,
        const float* __restrict__ spb, const float* __restrict__ ugb,
        const float* __restrict__ A_log, const float* __restrict__ Dp,
        const float* __restrict__ hstart, u16* __restrict__ yb)
{
    int e = blockIdx.x * 256 + threadIdx.x;
    int c = blockIdx.y;
    int b = blockIdx.z;
    float a[NST], h[NST];
    const float4* ap = reinterpret_cast<const float4*>(A_log + (size_t)e * NST);
    #pragma unroll
    for (int q = 0; q < 4; q++) {
        float4 v = ap[q];
        a[4*q+0] = -expf(v.x); a[4*q+1] = -expf(v.y);
        a[4*q+2] = -expf(v.z); a[4*q+3] = -expf(v.w);
    }
    const float* hs = hstart + (((size_t)(b * ED + e)) * NC + c) * NST;
    #pragma unroll
    for (int n = 0; n < NST; n++) h[n] = hs[n];
    float dpv = Dp[e];
    int m0 = b * LL + c * CL;
    for (int l = 0; l < CL; l++) {
        int m = m0 + l;
        float dtv = dtb[(size_t)m * ED + e];
        float ucv = ucb[(size_t)m * ED + e];
        const float4* bp = reinterpret_cast<const float4*>(spb + (size_t)m * SP + DTR);
        const float4* cp = reinterpret_cast<const float4*>(spb + (size_t)m * SP + DTR + NST);
        float g = ugb[(size_t)m * (2 * ED) + ED + e];
        float x = dtv * ucv;
        float y0 = 0.0f, y1 = 0.0f, y2 = 0.0f, y3 = 0.0f;
        #pragma unroll
        for (int q = 0; q < 4; q++) {
            float4 bv = bp[q];
            float4 cv = cp[q];
            h[4*q+0] = fmaf(expf(dtv * a[4*q+0]), h[4*q+0], x * bv.x);
            h[4*q+1] = fmaf(expf(dtv * a[4*q+1]), h[4*q+1], x * bv.y);
            h[4*q+2] = fmaf(expf(dtv * a[4*q+2]), h[4*q+2], x * bv.z);
            h[4*q+3] = fmaf(expf(dtv * a[4*q+3]), h[4*q+3], x * bv.w);
            y0 = fmaf(h[4*q+0], cv.x, y0);
            y1 = fmaf(h[4*q+1], cv.y, y1);
            y2 = fmaf(h[4*q+2], cv.z, y2);
            y3 = fmaf(h[4*q+3], cv.w, y3);
        }
        float yv = (y0 + y1) + (y2 + y3) + ucv * dpv;
        yb[(size_t)m * ED + e] = f2bf(yv * siluf(g));
    }
}

extern "C" void kernel_launch(void* const* d_in, const int* in_sizes, int n_in,
                              void* d_out, int out_size, void* d_ws, size_t ws_size,
                              hipStream_t stream) {
    const int*   src    = (const int*)  d_in[0];
    const float* emb    = (const float*)d_in[1];
    const float* norm_w = (const float*)d_in[2];
    const float* in_prj = (const float*)d_in[3];
    const float* conv_w = (const float*)d_in[4];
    const float* conv_b = (const float*)d_in[5];
    const float* x_prj  = (const float*)d_in[6];
    const float* dt_w   = (const float*)d_in[7];
    const float* dt_b   = (const float*)d_in[8];
    const float* A_log  = (const float*)d_in[9];
    const float* Dp     = (const float*)d_in[10];
    const float* out_p  = (const float*)d_in[11];
    const float* normf  = (const float*)d_in[12];
    float* out = (float*)d_out;

    float* ws    = (float*)d_ws;
    float* h     = ws;                              // M*D
    float* xn_f  = h     + (size_t)MM * DDIM;       // M*D slot (bf16 used)
    float* ug    = xn_f  + (size_t)MM * DDIM;       // M*2ED
    float* ucb   = ug    + (size_t)MM * 2 * ED;     // M*ED
    float* spb   = ucb   + (size_t)MM * ED;         // M*SP
    float* dtbf  = spb   + (size_t)MM * SP;         // M*ED
    float* yb_f  = dtbf  + (size_t)MM * ED;         // M*ED slot (bf16 used)
    float* hfin  = yb_f  + (size_t)MM * ED;         // B*ED*NC*NST
    float* sumdt = hfin  + (size_t)BB * ED * NC * NST; // B*ED*NC
    float* hstart= sumdt + (size_t)BB * ED * NC;    // B*ED*NC*NST
    float* wend  = hstart+ (size_t)BB * ED * NC * NST;

    u16* xn = (u16*)xn_f;
    u16* yb = (u16*)yb_f;
    u16* wbf_in  = (u16*)wend;                         // NL*2ED*D bf16
    u16* wbf_out = wbf_in  + (size_t)NL * 2 * ED * DDIM;  // NL*D*ED bf16
    u16* wbf_emb = wbf_out + (size_t)NL * DDIM * ED;      // V*D bf16
    float* opart = (float*)(wbf_emb + (size_t)VV * DDIM); // OPS * M*D fp32
    float* xpart = opart + (size_t)OPS * MM * DDIM;       // XKS * M*SP fp32

    // one-time weight conversion (bit-identical RNE rounding to old staging)
    cvt_bf16_kernel<<<2048, 256, 0, stream>>>(in_prj, wbf_in, NL * 2 * ED * DDIM / 4);
    cvt_bf16_kernel<<<2048, 256, 0, stream>>>(out_p, wbf_out, NL * DDIM * ED / 4);
    cvt_bf16_kernel<<<256, 256, 0, stream>>>(emb, wbf_emb, VV * DDIM / 4);

    embed_kernel<<<MM, 256, 0, stream>>>(src, emb, h);

    for (int layer = 0; layer < NL; layer++) {
        // rmsnorm; for layer>0 also folds in the 4 out_proj partials (h update)
        rmsnorm_res_kernel<<<MM, 256, 0, stream>>>(
            h, opart, layer == 0 ? 0 : OPS, norm_w + (size_t)layer * DDIM, xn);
        // ug = xn @ in_proj^T   [M, 2ED]  (grid 48x8 = 384 blocks, dbuf)
        gemm_bf16_d<2, 0><<<dim3(2 * ED / 64, MM / 128, 1), 256, 0, stream>>>(
            xn, DDIM, wbf_in + (size_t)layer * 2 * ED * DDIM, DDIM,
            ug, 2 * ED, DDIM);
        // sp partials = silu(conv(u)) @ x_proj^T; also writes ucb
        // (grid 16x32 = 512 blocks = 2.0/CU uniform)
        xproj_conv_partial<<<dim3(MM / 64, XKS), 256, 0, stream>>>(
            ug, conv_w + (size_t)layer * ED * KC, conv_b + (size_t)layer * ED,
            x_prj + (size_t)layer * SP * ED, xpart, ucb);
        xproj_reduce<<<MM * SP / 1024, 256, 0, stream>>>(xpart, spb);
        // dt = softplus(sp[:, :48] @ dt_w^T + dt_b)   [M, ED]   (fp32)
        sgemm_nt<<<dim3(MM / 64, ED / 64), 256, 0, stream>>>(
            spb, SP, dt_w + (size_t)layer * ED * DTR, DTR,
            dtbf, ED, ED, DTR, 1, dt_b + (size_t)layer * ED);
        // chunked scan
        scan_pass1<<<dim3(ED / 256, NC, BB), 256, 0, stream>>>(
            dtbf, ucb, spb, A_log + (size_t)layer * ED * NST, hfin, sumdt);
        scan_mid<<<BB * ED * NST / 256, 256, 0, stream>>>(
            hfin, sumdt, A_log + (size_t)layer * ED * NST, hstart);
        scan_pass2<<<dim3(ED / 256, NC, BB), 256, 0, stream>>>(
            dtbf, ucb, spb, ug, A_log + (size_t)layer * ED * NST,
            Dp + (size_t)layer * ED, hstart, yb);
        // out_proj partials: opart[z] = y @ out_proj^T[k-slice z]
        // (grid 12x8x4 = 384 blocks; reduction folds into next rmsnorm)
        gemm_bf16_d<2, 4><<<dim3(DDIM / 64, MM / 128, OPS), 256, 0, stream>>>(
            yb, ED, wbf_out + (size_t)layer * DDIM * ED, ED,
            opart, DDIM, OPK);
    }

    // final rmsnorm folds in last layer's out_proj partials
    rmsnorm_res_kernel<<<MM, 256, 0, stream>>>(h, opart, OPS, normf, xn);
    // logits = xn @ embed^T, stored transposed to [L, B, V]  (BN=32: 256 blk)
    gemm_bf16_d<1, 3><<<dim3(VV / 32, MM / 128, 1), 256, 0, stream>>>(
        xn, DDIM, wbf_emb, DDIM, out, VV, DDIM);
}

// Round 7
// 2882.552 us; speedup vs baseline: 1.4538x; 1.1706x over previous
//
#include <hip/hip_runtime.h>
#include <hip/hip_bf16.h>
#include <math.h>

// Problem dims (fixed by reference)
#define NL   24
#define DDIM 768
#define ED   1536
#define NST  16
#define KC   4
#define DTR  48
#define VV   1024
#define LL   512
#define BB   2
#define MM   (BB*LL)      // 1024
#define SP   80           // DT_RANK + 2N

// scan chunking
#define NC   32           // chunks per sequence
#define CL   (LL/NC)      // 16 timesteps per chunk

// x_proj split-K
#define XKS  32           // K splits (512 blocks = 2.0/CU uniform)
#define XKC  (ED/XKS)     // 48 per split

// out_proj split-K
#define OPS  4            // splits
#define OPK  (ED/OPS)     // 384 K per split

typedef unsigned short u16;
typedef __bf16 bf16x8 __attribute__((ext_vector_type(8)));
typedef float  floatx4 __attribute__((ext_vector_type(4)));
typedef unsigned short ushort4v __attribute__((ext_vector_type(4)));

typedef const __attribute__((address_space(1))) void gvoid_t;
typedef __attribute__((address_space(3))) void svoid_t;

// async global->LDS, 16B per lane; LDS dest = wave-uniform base + lane*16
#define GLD16(g, l) __builtin_amdgcn_global_load_lds((gvoid_t*)(g), (svoid_t*)(l), 16, 0, 0)

__device__ __forceinline__ float softplusf(float x) {
    return fmaxf(x, 0.0f) + log1pf(__expf(-fabsf(x)));
}
__device__ __forceinline__ float siluf(float x) {
    return x / (1.0f + __expf(-x));
}
__device__ __forceinline__ u16 f2bf(float x) {
    unsigned int u = __builtin_bit_cast(unsigned int, x);
    u += 0x7FFFu + ((u >> 16) & 1u);   // round-to-nearest-even
    return (u16)(u >> 16);
}

// ---------------- fp32 -> bf16 bulk conversion (weights, once per call) ----
__global__ __launch_bounds__(256) void cvt_bf16_kernel(
        const float* __restrict__ in, u16* __restrict__ out, int n4)
{
    int stride = gridDim.x * 256;
    for (int i = blockIdx.x * 256 + threadIdx.x; i < n4; i += stride) {
        float4 v = reinterpret_cast<const float4*>(in)[i];
        ushort4v o = {f2bf(v.x), f2bf(v.y), f2bf(v.z), f2bf(v.w)};
        reinterpret_cast<ushort4v*>(out)[i] = o;
    }
}

// ---------------- embedding: h[m,:] = embed[src[l,b],:], m = b*L + l -------
__global__ __launch_bounds__(256) void embed_kernel(
        const int* __restrict__ src, const float* __restrict__ emb,
        float* __restrict__ h)
{
    int m = blockIdx.x;
    int b = m >> 9;           // m / L
    int l = m & (LL - 1);
    int v = src[l * BB + b];
    const float* er = emb + (size_t)v * DDIM;
    float* hr = h + (size_t)m * DDIM;
    for (int d = threadIdx.x; d < DDIM; d += 256) hr[d] = er[d];
}

// ------- rmsnorm: read h (kept current by atomic out_proj), write bf16 xn --
__global__ __launch_bounds__(256) void rmsnorm_kernel(
        const float* __restrict__ h, const float* __restrict__ w,
        u16* __restrict__ o)
{
    __shared__ float red[4];
    int m = blockIdx.x, tid = threadIdx.x;
    const float* hr = h + (size_t)m * DDIM;
    float v0 = hr[tid], v1 = hr[tid + 256], v2 = hr[tid + 512];
    float s = v0 * v0 + v1 * v1 + v2 * v2;
    #pragma unroll
    for (int off = 32; off; off >>= 1) s += __shfl_down(s, off);
    if ((tid & 63) == 0) red[tid >> 6] = s;
    __syncthreads();
    float tot = red[0] + red[1] + red[2] + red[3];
    float scale = rsqrtf(tot * (1.0f / DDIM) + 1e-5f);
    u16* orow = o + (size_t)m * DDIM;
    orow[tid]       = f2bf(v0 * scale * w[tid]);
    orow[tid + 256] = f2bf(v1 * scale * w[tid + 256]);
    orow[tid + 512] = f2bf(v2 * scale * w[tid + 512]);
}

// ============ bf16 MFMA GEMM, BM=128 x BN=32*BNF, BK=64, double-buffered ===
// A bf16 [M,lda], W bf16 [N,ldb] row-major (K-contiguous). 4 waves in 2x2;
// wave tile 64 x BNF*16 (4 x BNF 16x16 MFMAs per 32-k step, 2 per BK).
// LDS: [row][64k] bf16, 8-u16 chunks XOR-swizzled (slot = chunk ^ (row&7))
// via pre-swizzled global source + linear global_load_lds dest.
// 2-phase pipeline: stage(next buf) issued BEFORE compute(cur); single
// __syncthreads per K-step (drains vmcnt+lgkm -> next buf ready, cur safe).
// grid: x = N-tiles (XCD-friendly), y = M-tiles, z = K-splits (Kper each).
// MODE: 0 = fp32 store; 3 = logits store with [B,L]->[L,B] transpose;
//       5 = atomicAdd into C (split-K accumulate, residual in place)
template<int BNF, int MODE>
__global__ __launch_bounds__(256) void gemm_bf16_d(
        const u16* __restrict__ A, int lda,
        const u16* __restrict__ W, int ldb,
        float* __restrict__ C, int ldc,
        int Kper)
{
    __shared__ __attribute__((aligned(16))) u16 As[2][128 * 64];
    __shared__ __attribute__((aligned(16))) u16 Bs[2][BNF * 32 * 64];
    int tid  = threadIdx.x;
    int lane = tid & 63;
    int wave = tid >> 6;
    int wm = wave >> 1, wn = wave & 1;
    int colBase = blockIdx.x * (BNF * 32);
    int rowBase = blockIdx.y * 128;
    int k0 = blockIdx.z * Kper;

    floatx4 acc[4][BNF];
    #pragma unroll
    for (int i = 0; i < 4; i++)
        #pragma unroll
        for (int j = 0; j < BNF; j++)
            acc[i][j] = (floatx4){0.f, 0.f, 0.f, 0.f};

    int kc = lane >> 4;      // k-chunk 0..3 within a 32-k MFMA step
    int lm = lane & 15;

    // staging: A has 1024 16B-chunks (4/thread), B has BNF*256 (BNF/thread).
    // chunk q -> row r=q>>3, LDS slot cs=q&7 holds global chunk cg=cs^(r&7).
    const u16* Ap[4];
    #pragma unroll
    for (int j = 0; j < 4; j++) {
        int q = (wave * 4 + j) * 64 + lane;
        int r = q >> 3, cg = (q & 7) ^ (r & 7);
        Ap[j] = A + (size_t)(rowBase + r) * lda + k0 + cg * 8;
    }
    const u16* Wp[BNF];
    #pragma unroll
    for (int j = 0; j < BNF; j++) {
        int q = (wave * BNF + j) * 64 + lane;
        int r = q >> 3, cg = (q & 7) ^ (r & 7);
        Wp[j] = W + (size_t)(colBase + r) * ldb + k0 + cg * 8;
    }

    auto stage = [&](int buf, int kk) {
        u16* as = &As[buf][0];
        u16* bs = &Bs[buf][0];
        #pragma unroll
        for (int j = 0; j < 4; j++) GLD16(Ap[j] + kk, as + (wave * 4 + j) * 512);
        #pragma unroll
        for (int j = 0; j < BNF; j++) GLD16(Wp[j] + kk, bs + (wave * BNF + j) * 512);
    };

    int nt = Kper >> 6;
    stage(0, 0);
    __syncthreads();
    for (int t = 0; t < nt; t++) {
        int cur = t & 1;
        if (t + 1 < nt) stage(cur ^ 1, (t + 1) * 64);
        #pragma unroll
        for (int ks = 0; ks < 2; ks++) {
            int ck = ks * 4 + kc;
            bf16x8 af[4], bw[BNF];
            #pragma unroll
            for (int i = 0; i < 4; i++) {
                int m = wm * 64 + i * 16 + lm;
                af[i] = *reinterpret_cast<const bf16x8*>(
                    &As[cur][m * 64 + ((ck ^ (m & 7)) * 8)]);
            }
            #pragma unroll
            for (int j = 0; j < BNF; j++) {
                int n = wn * (BNF * 16) + j * 16 + lm;
                bw[j] = *reinterpret_cast<const bf16x8*>(
                    &Bs[cur][n * 64 + ((ck ^ (n & 7)) * 8)]);
            }
            #pragma unroll
            for (int i = 0; i < 4; i++)
                #pragma unroll
                for (int j = 0; j < BNF; j++)
                    acc[i][j] = __builtin_amdgcn_mfma_f32_16x16x32_bf16(
                        af[i], bw[j], acc[i][j], 0, 0, 0);
        }
        __syncthreads();   // drains lgkm (cur reads done) + vmcnt (next ready)
    }

    // epilogue: D col = lane&15, row = (lane>>4)*4 + reg
    int c4 = (lane >> 4) * 4;
    #pragma unroll
    for (int i = 0; i < 4; i++) {
        #pragma unroll
        for (int j = 0; j < BNF; j++) {
            floatx4 v = acc[i][j];
            int col = colBase + wn * (BNF * 16) + j * 16 + lm;
            #pragma unroll
            for (int p = 0; p < 4; p++) {
                int row = rowBase + wm * 64 + i * 16 + c4 + p;
                if (MODE == 3) {
                    int l = row & (LL - 1), b = row >> 9;
                    C[((size_t)l * BB + b) * ldc + col] = v[p];
                } else if (MODE == 5) {
                    atomicAdd(&C[(size_t)row * ldc + col], v[p]);
                } else {
                    C[(size_t)row * ldc + col] = v[p];
                }
            }
        }
    }
}

// ---------------- generic fp32 SGEMM (dt GEMM) -----------------------------
// modes: 0 = store; 1 = softplus(acc + bias[n])
__global__ __launch_bounds__(256) void sgemm_nt(
        const float* __restrict__ A, int lda,
        const float* __restrict__ W, int ldb,
        float* __restrict__ C, int ldc,
        int Nmat, int Kdim, int mode, const float* __restrict__ bias)
{
    __shared__ float As[16][65];
    __shared__ float Ws[16][65];
    int tid = threadIdx.x;
    int tx = tid & 15, ty = tid >> 4;
    int rowBase = blockIdx.x * 64;
    int colBase = blockIdx.y * 64;
    float acc[4][4] = {};

    for (int kk = 0; kk < Kdim; kk += 16) {
        #pragma unroll
        for (int i = 0; i < 4; i++) {
            int idx = tid + i * 256;
            int r = idx >> 4, kc = idx & 15;
            As[kc][r] = A[(size_t)(rowBase + r) * lda + kk + kc];
            int cG = colBase + r;
            Ws[kc][r] = (cG < Nmat) ? W[(size_t)cG * ldb + kk + kc] : 0.0f;
        }
        __syncthreads();
        #pragma unroll
        for (int k = 0; k < 16; k++) {
            float av[4], bv[4];
            #pragma unroll
            for (int i = 0; i < 4; i++) av[i] = As[k][ty + 16 * i];
            #pragma unroll
            for (int j = 0; j < 4; j++) bv[j] = Ws[k][tx + 16 * j];
            #pragma unroll
            for (int i = 0; i < 4; i++)
                #pragma unroll
                for (int j = 0; j < 4; j++)
                    acc[i][j] = fmaf(av[i], bv[j], acc[i][j]);
        }
        __syncthreads();
    }

    #pragma unroll
    for (int i = 0; i < 4; i++) {
        int m = rowBase + ty + 16 * i;
        #pragma unroll
        for (int j = 0; j < 4; j++) {
            int n = colBase + tx + 16 * j;
            if (n >= Nmat) continue;
            float v = acc[i][j];
            if (mode == 0) {
                C[(size_t)m * ldc + n] = v;
            } else {
                C[(size_t)m * ldc + n] = softplusf(v + bias[n]);
            }
        }
    }
}

// -------- x_proj split-K with fused depthwise conv + SiLU ------------------
// grid (MM/64, XKS), block 256. A-tile elements uc[m][e] are computed on the
// fly from ug (causal K=4 conv + bias + SiLU), used for the GEMM AND written
// to ucb (each (m,e) computed exactly once across the grid).
__global__ __launch_bounds__(256) void xproj_conv_partial(
        const float* __restrict__ ug, const float* __restrict__ cw,
        const float* __restrict__ cb, const float* __restrict__ W,
        float* __restrict__ part, float* __restrict__ ucb)
{
    __shared__ float As[16][65];
    __shared__ float Ws[16][88];
    int tid = threadIdx.x;
    int tx = tid & 15;        // col base (5 cols spaced 16)
    int ty = tid >> 4;        // row base (4 rows spaced 16)
    int rowBase = blockIdx.x * 64;
    int k0 = blockIdx.y * XKC;
    float acc[4][5] = {};

    for (int kk = 0; kk < XKC; kk += 16) {
        #pragma unroll
        for (int i = 0; i < 4; i++) {
            int idx = tid + i * 256;
            int r = idx >> 4, kc = idx & 15;
            int m = rowBase + r;
            int e = k0 + kk + kc;
            int b = m >> 9, l = m & (LL - 1);
            float a = cb[e];
            #pragma unroll
            for (int k = 0; k < KC; k++) {
                int ll = l + k - (KC - 1);
                float uv = (ll >= 0) ? ug[((size_t)(b * LL + ll)) * (2 * ED) + e] : 0.0f;
                a = fmaf(uv, cw[e * KC + k], a);
            }
            a = siluf(a);
            As[kc][r] = a;
            ucb[(size_t)m * ED + e] = a;
        }
        #pragma unroll
        for (int i = 0; i < 5; i++) {
            int idx = tid + i * 256;        // 0..1279
            int c = idx >> 4, kc = idx & 15;
            Ws[kc][c] = W[(size_t)c * ED + k0 + kk + kc];
        }
        __syncthreads();
        #pragma unroll
        for (int k = 0; k < 16; k++) {
            float av[4], bv[5];
            #pragma unroll
            for (int i = 0; i < 4; i++) av[i] = As[k][ty + 16 * i];
            #pragma unroll
            for (int j = 0; j < 5; j++) bv[j] = Ws[k][tx + 16 * j];
            #pragma unroll
            for (int i = 0; i < 4; i++)
                #pragma unroll
                for (int j = 0; j < 5; j++)
                    acc[i][j] = fmaf(av[i], bv[j], acc[i][j]);
        }
        __syncthreads();
    }

    float* p = part + ((size_t)blockIdx.y * MM + rowBase) * SP;
    #pragma unroll
    for (int i = 0; i < 4; i++)
        #pragma unroll
        for (int j = 0; j < 5; j++)
            p[(ty + 16 * i) * SP + tx + 16 * j] = acc[i][j];
}

// reduce XKS partial slices -> spb[m][0:80]  (float4 vectorized)
__global__ __launch_bounds__(256) void xproj_reduce(
        const float* __restrict__ part, float* __restrict__ spb)
{
    int idx = blockIdx.x * 256 + threadIdx.x;   // over MM*SP/4 = 20480
    float4 s = {0.f, 0.f, 0.f, 0.f};
    #pragma unroll
    for (int ks = 0; ks < XKS; ks++) {
        float4 v = reinterpret_cast<const float4*>(part + (size_t)ks * MM * SP)[idx];
        s.x += v.x; s.y += v.y; s.z += v.z; s.w += v.w;
    }
    reinterpret_cast<float4*>(spb)[idx] = s;
}

// ================= chunked selective scan ==================================
__global__ __launch_bounds__(256) void scan_pass1(
        const float* __restrict__ dtb, const float* __restrict__ ucb,
        const float* __restrict__ spb, const float* __restrict__ A_log,
        float* __restrict__ hfin, float* __restrict__ sumdt)
{
    int e = blockIdx.x * 256 + threadIdx.x;
    int c = blockIdx.y;
    int b = blockIdx.z;
    float a[NST], h[NST];
    const float4* ap = reinterpret_cast<const float4*>(A_log + (size_t)e * NST);
    #pragma unroll
    for (int q = 0; q < 4; q++) {
        float4 v = ap[q];
        a[4*q+0] = -__expf(v.x); a[4*q+1] = -__expf(v.y);
        a[4*q+2] = -__expf(v.z); a[4*q+3] = -__expf(v.w);
    }
    #pragma unroll
    for (int n = 0; n < NST; n++) h[n] = 0.0f;
    float sdt = 0.0f;
    int m0 = b * LL + c * CL;
    for (int l = 0; l < CL; l++) {
        int m = m0 + l;
        float dtv = dtb[(size_t)m * ED + e];
        float ucv = ucb[(size_t)m * ED + e];
        const float4* bp = reinterpret_cast<const float4*>(spb + (size_t)m * SP + DTR);
        float x = dtv * ucv;
        sdt += dtv;
        #pragma unroll
        for (int q = 0; q < 4; q++) {
            float4 bv = bp[q];
            h[4*q+0] = fmaf(__expf(dtv * a[4*q+0]), h[4*q+0], x * bv.x);
            h[4*q+1] = fmaf(__expf(dtv * a[4*q+1]), h[4*q+1], x * bv.y);
            h[4*q+2] = fmaf(__expf(dtv * a[4*q+2]), h[4*q+2], x * bv.z);
            h[4*q+3] = fmaf(__expf(dtv * a[4*q+3]), h[4*q+3], x * bv.w);
        }
    }
    float* hf = hfin + (((size_t)(b * ED + e)) * NC + c) * NST;
    #pragma unroll
    for (int n = 0; n < NST; n++) hf[n] = h[n];
    sumdt[((size_t)(b * ED + e)) * NC + c] = sdt;
}

__global__ __launch_bounds__(256) void scan_mid(
        const float* __restrict__ hfin, const float* __restrict__ sumdt,
        const float* __restrict__ A_log, float* __restrict__ hstart)
{
    int gid = blockIdx.x * 256 + threadIdx.x;   // (b*ED+e)*16 + n
    int n = gid & 15;
    int be = gid >> 4;
    int e = be % ED;
    float a = -__expf(A_log[(size_t)e * NST + n]);
    float h = 0.0f;
    const float* hf = hfin + (size_t)be * NC * NST;
    const float* sd = sumdt + (size_t)be * NC;
    float* hs = hstart + (size_t)be * NC * NST;
    for (int c = 0; c < NC; c++) {
        hs[c * NST + n] = h;
        h = fmaf(__expf(a * sd[c]), h, hf[c * NST + n]);
    }
}

__global__ __launch_bounds__(256) void scan_pass2(
        const float* __restrict__ dtb, const float* __restrict__ ucb,
        const float* __restrict__ spb, const float* __restrict__ ugb,
        const float* __restrict__ A_log, const float* __restrict__ Dp,
        const float* __restrict__ hstart, u16* __restrict__ yb)
{
    int e = blockIdx.x * 256 + threadIdx.x;
    int c = blockIdx.y;
    int b = blockIdx.z;
    float a[NST], h[NST];
    const float4* ap = reinterpret_cast<const float4*>(A_log + (size_t)e * NST);
    #pragma unroll
    for (int q = 0; q < 4; q++) {
        float4 v = ap[q];
        a[4*q+0] = -__expf(v.x); a[4*q+1] = -__expf(v.y);
        a[4*q+2] = -__expf(v.z); a[4*q+3] = -__expf(v.w);
    }
    const float* hs = hstart + (((size_t)(b * ED + e)) * NC + c) * NST;
    #pragma unroll
    for (int n = 0; n < NST; n++) h[n] = hs[n];
    float dpv = Dp[e];
    int m0 = b * LL + c * CL;
    for (int l = 0; l < CL; l++) {
        int m = m0 + l;
        float dtv = dtb[(size_t)m * ED + e];
        float ucv = ucb[(size_t)m * ED + e];
        const float4* bp = reinterpret_cast<const float4*>(spb + (size_t)m * SP + DTR);
        const float4* cp = reinterpret_cast<const float4*>(spb + (size_t)m * SP + DTR + NST);
        float g = ugb[(size_t)m * (2 * ED) + ED + e];
        float x = dtv * ucv;
        float y0 = 0.0f, y1 = 0.0f, y2 = 0.0f, y3 = 0.0f;
        #pragma unroll
        for (int q = 0; q < 4; q++) {
            float4 bv = bp[q];
            float4 cv = cp[q];
            h[4*q+0] = fmaf(__expf(dtv * a[4*q+0]), h[4*q+0], x * bv.x);
            h[4*q+1] = fmaf(__expf(dtv * a[4*q+1]), h[4*q+1], x * bv.y);
            h[4*q+2] = fmaf(__expf(dtv * a[4*q+2]), h[4*q+2], x * bv.z);
            h[4*q+3] = fmaf(__expf(dtv * a[4*q+3]), h[4*q+3], x * bv.w);
            y0 = fmaf(h[4*q+0], cv.x, y0);
            y1 = fmaf(h[4*q+1], cv.y, y1);
            y2 = fmaf(h[4*q+2], cv.z, y2);
            y3 = fmaf(h[4*q+3], cv.w, y3);
        }
        float yv = (y0 + y1) + (y2 + y3) + ucv * dpv;
        yb[(size_t)m * ED + e] = f2bf(yv * siluf(g));
    }
}

extern "C" void kernel_launch(void* const* d_in, const int* in_sizes, int n_in,
                              void* d_out, int out_size, void* d_ws, size_t ws_size,
                              hipStream_t stream) {
    const int*   src    = (const int*)  d_in[0];
    const float* emb    = (const float*)d_in[1];
    const float* norm_w = (const float*)d_in[2];
    const float* in_prj = (const float*)d_in[3];
    const float* conv_w = (const float*)d_in[4];
    const float* conv_b = (const float*)d_in[5];
    const float* x_prj  = (const float*)d_in[6];
    const float* dt_w   = (const float*)d_in[7];
    const float* dt_b   = (const float*)d_in[8];
    const float* A_log  = (const float*)d_in[9];
    const float* Dp     = (const float*)d_in[10];
    const float* out_p  = (const float*)d_in[11];
    const float* normf  = (const float*)d_in[12];
    float* out = (float*)d_out;

    float* ws    = (float*)d_ws;
    float* h     = ws;                              // M*D
    float* xn_f  = h     + (size_t)MM * DDIM;       // M*D slot (bf16 used)
    float* ug    = xn_f  + (size_t)MM * DDIM;       // M*2ED
    float* ucb   = ug    + (size_t)MM * 2 * ED;     // M*ED
    float* spb   = ucb   + (size_t)MM * ED;         // M*SP
    float* dtbf  = spb   + (size_t)MM * SP;         // M*ED
    float* yb_f  = dtbf  + (size_t)MM * ED;         // M*ED slot (bf16 used)
    float* hfin  = yb_f  + (size_t)MM * ED;         // B*ED*NC*NST
    float* sumdt = hfin  + (size_t)BB * ED * NC * NST; // B*ED*NC
    float* hstart= sumdt + (size_t)BB * ED * NC;    // B*ED*NC*NST
    float* wend  = hstart+ (size_t)BB * ED * NC * NST;

    u16* xn = (u16*)xn_f;
    u16* yb = (u16*)yb_f;
    u16* wbf_in  = (u16*)wend;                         // NL*2ED*D bf16
    u16* wbf_out = wbf_in  + (size_t)NL * 2 * ED * DDIM;  // NL*D*ED bf16
    u16* wbf_emb = wbf_out + (size_t)NL * DDIM * ED;      // V*D bf16
    float* xpart = (float*)(wbf_emb + (size_t)VV * DDIM); // XKS * M*SP fp32

    // one-time weight conversion (bit-identical RNE rounding to old staging)
    cvt_bf16_kernel<<<2048, 256, 0, stream>>>(in_prj, wbf_in, NL * 2 * ED * DDIM / 4);
    cvt_bf16_kernel<<<2048, 256, 0, stream>>>(out_p, wbf_out, NL * DDIM * ED / 4);
    cvt_bf16_kernel<<<256, 256, 0, stream>>>(emb, wbf_emb, VV * DDIM / 4);

    embed_kernel<<<MM, 256, 0, stream>>>(src, emb, h);

    for (int layer = 0; layer < NL; layer++) {
        // rmsnorm (h kept current in place by atomic out_proj epilogue)
        rmsnorm_kernel<<<MM, 256, 0, stream>>>(
            h, norm_w + (size_t)layer * DDIM, xn);
        // ug = xn @ in_proj^T   [M, 2ED]  (grid 48x8 = 384 blocks, dbuf)
        gemm_bf16_d<2, 0><<<dim3(2 * ED / 64, MM / 128, 1), 256, 0, stream>>>(
            xn, DDIM, wbf_in + (size_t)layer * 2 * ED * DDIM, DDIM,
            ug, 2 * ED, DDIM);
        // sp partials = silu(conv(u)) @ x_proj^T; also writes ucb
        // (grid 16x32 = 512 blocks = 2.0/CU uniform)
        xproj_conv_partial<<<dim3(MM / 64, XKS), 256, 0, stream>>>(
            ug, conv_w + (size_t)layer * ED * KC, conv_b + (size_t)layer * ED,
            x_prj + (size_t)layer * SP * ED, xpart, ucb);
        xproj_reduce<<<MM * SP / 1024, 256, 0, stream>>>(xpart, spb);
        // dt = softplus(sp[:, :48] @ dt_w^T + dt_b)   [M, ED]   (fp32)
        sgemm_nt<<<dim3(MM / 64, ED / 64), 256, 0, stream>>>(
            spb, SP, dt_w + (size_t)layer * ED * DTR, DTR,
            dtbf, ED, ED, DTR, 1, dt_b + (size_t)layer * ED);
        // chunked scan
        scan_pass1<<<dim3(ED / 256, NC, BB), 256, 0, stream>>>(
            dtbf, ucb, spb, A_log + (size_t)layer * ED * NST, hfin, sumdt);
        scan_mid<<<BB * ED * NST / 256, 256, 0, stream>>>(
            hfin, sumdt, A_log + (size_t)layer * ED * NST, hstart);
        scan_pass2<<<dim3(ED / 256, NC, BB), 256, 0, stream>>>(
            dtbf, ucb, spb, ug, A_log + (size_t)layer * ED * NST,
            Dp + (size_t)layer * ED, hstart, yb);
        // h += y @ out_proj^T (atomic split-K accumulate, grid 12x8x4)
        gemm_bf16_d<2, 5><<<dim3(DDIM / 64, MM / 128, OPS), 256, 0, stream>>>(
            yb, ED, wbf_out + (size_t)layer * DDIM * ED, ED,
            h, DDIM, OPK);
    }

    // final rmsnorm
    rmsnorm_kernel<<<MM, 256, 0, stream>>>(h, normf, xn);
    // logits = xn @ embed^T, stored transposed to [L, B, V]  (BN=32: 256 blk)
    gemm_bf16_d<1, 3><<<dim3(VV / 32, MM / 128, 1), 256, 0, stream>>>(
        xn, DDIM, wbf_emb, DDIM, out, VV, DDIM);
}